// Round 14
// baseline (1709.156 us; speedup 1.0000x reference)
//
#include <hip/hip_runtime.h>
#include <hip/hip_bf16.h>
#include <cstdint>
#include <cstddef>

#define B_ 64
#define T_ 512
#define E_ 512
#define H_ 1024
#define V_ 32000

typedef __attribute__((ext_vector_type(8))) short bf16x8;
typedef __attribute__((ext_vector_type(4))) float f32x4;
typedef __attribute__((ext_vector_type(4))) float float4_t;
typedef unsigned long long ull;
typedef unsigned int u32;

static __device__ __forceinline__ unsigned short f2b(float f) {
  union { float f; u32 u; } v; v.f = f;
  u32 u = v.u;
  u32 r = (u + 0x7FFFu + ((u >> 16) & 1u)) >> 16;  // RNE
  return (unsigned short)r;
}
static __device__ __forceinline__ float b2f(unsigned short s) {
  union { u32 u; float f; } v; v.u = ((u32)s) << 16;
  return v.f;
}
// fast tanh: 1 - 2/(e^{2x}+1); v_exp_f32 + v_rcp_f32. rel err ~1e-6 << bf16.
static __device__ __forceinline__ float ftanh(float x) {
  float z = __builtin_amdgcn_exp2f(x * 2.8853900817779268f);  // e^{2x}
  return 1.0f - 2.0f * __builtin_amdgcn_rcpf(z + 1.0f);
}
static __device__ __forceinline__ bf16x8 cvt8(const float* p) {
  bf16x8 r;
#pragma unroll
  for (int i = 0; i < 8; i++) r[i] = (short)f2b(p[i]);
  return r;
}
// relaxed agent-scope (sc1) ops: coherent at MALL, no cache maintenance
static __device__ __forceinline__ ull ald(const ull* p) {
  return __hip_atomic_load(p, __ATOMIC_RELAXED, __HIP_MEMORY_SCOPE_AGENT);
}
static __device__ __forceinline__ void ast64(ull* p, ull v) {
  __hip_atomic_store(p, v, __ATOMIC_RELAXED, __HIP_MEMORY_SCOPE_AGENT);
}
static __device__ __forceinline__ void ast32(u32* p, u32 v) {
  __hip_atomic_store(p, v, __ATOMIC_RELAXED, __HIP_MEMORY_SCOPE_AGENT);
}
// LDS swizzle for 128-byte rows: spread rows across banks
static __device__ __forceinline__ int swz128(int row, int byte_off) {
  return row * 128 + (byte_off ^ ((row & 7) << 4));
}

// ---------------- init: clear epoch-tagged exchange buffers ----------------
// MUST run every launch: tags surviving a graph replay would short-circuit
// the waits (forbidden cross-call state). 3*64*1024 = 196608 u32.
__global__ void k_init(u32* xb) {
  int i = blockIdx.x * blockDim.x + threadIdx.x;
  ast32(xb + i, 0u);
}

// ---------------- E2 = emb @ W_ih^T  [V,H] bf16 ----------------
// 128x128 tile, 4 waves, 2x8 frags/wave, BK=64. grid (8, 250). (R12-proven)
__global__ __launch_bounds__(256)
void k_e2(const float* __restrict__ emb, const float* __restrict__ Wih,
          unsigned short* __restrict__ E2) {
  __shared__ unsigned char As[128 * 128];
  __shared__ unsigned char Bs[128 * 128];
  const int tid = threadIdx.x;
  const int lane = tid & 63;
  const int w = tid >> 6;                   // 0..3 (M sub-tile of 32 rows)
  const int n0 = blockIdx.x * 128;          // over H
  const int m0 = blockIdx.y * 128;          // over V
  f32x4 acc[2][8];
#pragma unroll
  for (int mi = 0; mi < 2; mi++)
#pragma unroll
    for (int nt = 0; nt < 8; nt++) acc[mi][nt] = (f32x4)0.0f;

  for (int kc = 0; kc < E_ / 64; kc++) {
    const int k0 = kc * 64;
    __syncthreads();
#pragma unroll
    for (int it = 0; it < 8; it++) {
      int idx = tid + it * 256;             // 0..2047 chunks of f32x4
      int r = idx >> 4;                     // 0..127
      int k4 = (idx & 15) * 4;              // 0..60
      float ta[4], tb[4];
      *(float4_t*)ta = *(const float4_t*)(emb + (size_t)(m0 + r) * E_ + k0 + k4);
      *(float4_t*)tb = *(const float4_t*)(Wih + (size_t)(n0 + r) * E_ + k0 + k4);
      unsigned short pa[4], pb[4];
#pragma unroll
      for (int q = 0; q < 4; q++) { pa[q] = f2b(ta[q]); pb[q] = f2b(tb[q]); }
      *(ull*)(As + swz128(r, k4 * 2)) = *(ull*)pa;
      *(ull*)(Bs + swz128(r, k4 * 2)) = *(ull*)pb;
    }
    __syncthreads();
#pragma unroll
    for (int kk = 0; kk < 2; kk++) {
      int kb = kk * 64 + (lane >> 4) * 16;
      bf16x8 a0 = *(const bf16x8*)(As + swz128(w * 32 + (lane & 15), kb));
      bf16x8 a1 = *(const bf16x8*)(As + swz128(w * 32 + 16 + (lane & 15), kb));
#pragma unroll
      for (int nt = 0; nt < 8; nt++) {
        bf16x8 b = *(const bf16x8*)(Bs + swz128(nt * 16 + (lane & 15), kb));
        acc[0][nt] = __builtin_amdgcn_mfma_f32_16x16x32_bf16(a0, b, acc[0][nt], 0, 0, 0);
        acc[1][nt] = __builtin_amdgcn_mfma_f32_16x16x32_bf16(a1, b, acc[1][nt], 0, 0, 0);
      }
    }
  }
#pragma unroll
  for (int mi = 0; mi < 2; mi++)
#pragma unroll
    for (int nt = 0; nt < 8; nt++)
#pragma unroll
      for (int reg = 0; reg < 4; reg++) {
        int row = m0 + w * 32 + mi * 16 + (lane >> 4) * 4 + reg;
        int col = n0 + nt * 16 + (lane & 15);
        E2[(size_t)row * H_ + col] = f2b(acc[mi][nt][reg]);
      }
}

// ---------------- persistent scan over T ----------------
// R13 structure (R10 geometry + R11 tagged protocol + ftanh) with two safe,
// register-neutral trims:
//  (a) first pull attempt's 8 loads hoisted BEFORE the xi gather, so the
//      first tag check's vmcnt doesn't wait on E2's L2-miss latency;
//  (b) group hist rows preloaded to LDS once ([8][516] padded, bank-free)
//      removing the per-step global tok load from the xi chain.
// Spin-loop live set unchanged (8 ull) — R12 lesson: unified reg file is
// exactly full at 128 VGPR + 128 AGPR; never widen the spin loop.
__global__ __launch_bounds__(512, 1)
void k_scan(const int* __restrict__ hist, const float* __restrict__ Whh,
            const unsigned short* __restrict__ E2,
            u32* __restrict__ xb,         // [3][64][1024] tagged words
            unsigned short* __restrict__ hbf, float* __restrict__ out_h) {
  const int tid = threadIdx.x;
  const int lane = tid & 63;
  const int w = tid >> 6;                 // wave id 0..7
  const int bid = blockIdx.x;
  const int g = bid & 7;                  // group (batch rows 8g..8g+8)
  const int j = bid >> 3;                 // col-slice id 0..7
  const int row0 = g * 8;                 // global batch-row base
  const int wcol0 = j * 128 + w * 16;     // this wave's 16 output cols

  __shared__ unsigned char hs[8 * 2048];  // h slice [8 rows][1024] bf16, swz
  __shared__ int tok_s[8 * 516];          // group hist rows, padded

  const int ar = lane & 15;               // frag row: outcol (A) / batch (B,D)
  const int a7 = ar & 7;                  // valid batch row index
  const int hi = lane >> 4;               // 0..3 k-group

  // W-frags (MFMA A): lane holds W_hh[wcol0+ar][kk*32 + hi*8 .. +8)
  bf16x8 Wreg[32];
  {
    const float* wrow = Whh + (size_t)(wcol0 + ar) * H_ + hi * 8;
#pragma unroll
    for (int kk = 0; kk < 32; kk++) {
      float tmp[8];
      *(float4_t*)(tmp)     = *(const float4_t*)(wrow + kk * 32);
      *(float4_t*)(tmp + 4) = *(const float4_t*)(wrow + kk * 32 + 4);
      Wreg[kk] = cvt8(tmp);
    }
  }

  // preload group's hist rows (8 x 512 ints) into LDS
  for (int i = tid; i < 8 * 512; i += 512)
    tok_s[(i >> 9) * 516 + (i & 511)] = hist[(size_t)(row0 + (i >> 9)) * T_ + (i & 511)];
  __syncthreads();

  for (int t = 0; t < T_; t++) {
    const u32* rbuf = xb + (size_t)((t + 2) % 3) * (B_ * H_);
    const ull* src = (const ull*)(rbuf + (size_t)(row0 + w) * H_);
    const u32 tagv = (u32)t << 16;
    ull hv[8];

    // (a) issue first pull attempt BEFORE xi gather
    if (t > 0) {
#pragma unroll
      for (int i = 0; i < 8; i++) hv[i] = ald(src + lane + 64 * i);
    }

    // xi gather: tok from LDS, ONE 8B E2 load per lane
    float xiv[4];
    {
      const int tok = tok_s[a7 * 516 + t];
      const ull xw = *(const ull*)(E2 + (size_t)tok * H_ + wcol0 + hi * 4);
      xiv[0] = b2f((unsigned short)xw);
      xiv[1] = b2f((unsigned short)(xw >> 16));
      xiv[2] = b2f((unsigned short)(xw >> 32));
      xiv[3] = b2f((unsigned short)(xw >> 48));
    }

    f32x4 acc0 = (f32x4)0.0f, acc1 = (f32x4)0.0f;

    if (t > 0) {
      // ---- self-validating pull (check first, reload on fail) ----
      for (;;) {
        u32 bad = 0;
#pragma unroll
        for (int i = 0; i < 8; i++)
          bad |= (((u32)hv[i] ^ tagv) | ((u32)(hv[i] >> 32) ^ tagv)) &
                 0xFFFF0000u;
        if (__all(bad == 0)) break;
        __builtin_amdgcn_s_sleep(1);
#pragma unroll
        for (int i = 0; i < 8; i++) hv[i] = ald(src + lane + 64 * i);
      }
      // strip tags, stage to LDS (same layout/swizzle as R10/R11/R13)
      {
        unsigned char* hsb = hs + w * 2048;
        const int sw = w << 4;
#pragma unroll
        for (int i = 0; i < 8; i++) {
          u32 p = ((u32)hv[i] & 0xFFFFu) | ((u32)(hv[i] >> 32) << 16);
          *(u32*)(hsb + ((lane * 4 + i * 256) ^ sw)) = p;
        }
      }
      __syncthreads();

      // D[m=outcol][n=batch] = sum_k W[outcol][k] * h[batch][k]
      const unsigned char* brow = hs + a7 * 2048;
      const int swb = a7 << 4;
#pragma unroll
      for (int kk = 0; kk < 32; kk += 2) {
        bf16x8 b0 = *(const bf16x8*)(brow + (((kk)     * 64 + hi * 16) ^ swb));
        bf16x8 b1 = *(const bf16x8*)(brow + (((kk + 1) * 64 + hi * 16) ^ swb));
        acc0 = __builtin_amdgcn_mfma_f32_16x16x32_bf16(Wreg[kk],     b0, acc0, 0, 0, 0);
        acc1 = __builtin_amdgcn_mfma_f32_16x16x32_bf16(Wreg[kk + 1], b1, acc1, 0, 0, 0);
      }
    }

    // epilogue: tagged store — fire-and-forget (store IS the signal)
    if (ar < 8) {
      float hval[4];
#pragma unroll
      for (int reg = 0; reg < 4; reg++)
        hval[reg] = ftanh(acc0[reg] + acc1[reg] + xiv[reg]);
      const u32 tagw = (u32)(t + 1) << 16;
      ull lo = (ull)(tagw | f2b(hval[0])) | ((ull)(tagw | f2b(hval[1])) << 32);
      ull hi2 = (ull)(tagw | f2b(hval[2])) | ((ull)(tagw | f2b(hval[3])) << 32);
      u32* wbuf = xb + (size_t)(t % 3) * (B_ * H_);
      ull* dst = (ull*)(wbuf + (size_t)(row0 + ar) * H_ + wcol0 + hi * 4);
      ast64(dst, lo);
      ast64(dst + 1, hi2);
      if (t == T_ - 1) {
        float4_t o = {hval[0], hval[1], hval[2], hval[3]};
        *(float4_t*)(out_h + (size_t)(row0 + ar) * H_ + wcol0 + hi * 4) = o;
        unsigned short* hp = hbf + (size_t)(row0 + ar) * H_ + wcol0 + hi * 4;
        hp[0] = f2b(hval[0]); hp[1] = f2b(hval[1]);
        hp[2] = f2b(hval[2]); hp[3] = f2b(hval[3]);
      }
    }
  }
}

// ---------------- logits = h_final @ W_cls^T + b ----------------
// grid 500 blocks (64 vocab cols each), 256 threads
__global__ __launch_bounds__(256)
void k_logits(const unsigned short* __restrict__ hb,
              const float* __restrict__ Wcls, const float* __restrict__ bcls,
              float* __restrict__ out) {
  __shared__ unsigned char Bs[64 * 128];
  const int tid = threadIdx.x;
  const int lane = tid & 63;
  const int w = tid >> 6;
  const int n0 = blockIdx.x * 64;
  f32x4 acc[4];
#pragma unroll
  for (int i = 0; i < 4; i++) acc[i] = (f32x4)0.0f;

  for (int kc = 0; kc < H_ / 64; kc++) {
    const int k0 = kc * 64;
    __syncthreads();
#pragma unroll
    for (int it = 0; it < 2; it++) {
      int idx = tid + it * 256;
      int r = idx >> 3;
      int k = (idx & 7) * 8;
      float tmp[8];
      *(float4_t*)(tmp)     = *(const float4_t*)(Wcls + (size_t)(n0 + r) * H_ + k0 + k);
      *(float4_t*)(tmp + 4) = *(const float4_t*)(Wcls + (size_t)(n0 + r) * H_ + k0 + k + 4);
      *(bf16x8*)(Bs + swz128(r, k * 2)) = cvt8(tmp);
    }
    __syncthreads();
#pragma unroll
    for (int kk = 0; kk < 2; kk++) {
      const unsigned short* ap =
          hb + (size_t)(w * 16 + (lane & 15)) * H_ + k0 + kk * 32 + (lane >> 4) * 8;
      bf16x8 a = *(const bf16x8*)ap;
      int kb = kk * 64 + (lane >> 4) * 16;
#pragma unroll
      for (int nt = 0; nt < 4; nt++) {
        bf16x8 b = *(const bf16x8*)(Bs + swz128(nt * 16 + (lane & 15), kb));
        acc[nt] = __builtin_amdgcn_mfma_f32_16x16x32_bf16(a, b, acc[nt], 0, 0, 0);
      }
    }
  }
#pragma unroll
  for (int nt = 0; nt < 4; nt++) {
    int col = n0 + nt * 16 + (lane & 15);
    float bias = bcls[col];
#pragma unroll
    for (int reg = 0; reg < 4; reg++) {
      int row = w * 16 + (lane >> 4) * 4 + reg;
      out[(size_t)row * V_ + col] = acc[nt][reg] + bias;
    }
  }
}

extern "C" void kernel_launch(void* const* d_in, const int* in_sizes, int n_in,
                              void* d_out, int out_size, void* d_ws, size_t ws_size,
                              hipStream_t stream) {
  const int*   hist = (const int*)d_in[0];
  const float* emb  = (const float*)d_in[1];
  const float* Wih  = (const float*)d_in[2];
  const float* Whh  = (const float*)d_in[3];
  const float* Wcls = (const float*)d_in[4];
  const float* bcls = (const float*)d_in[5];
  float* out = (float*)d_out;

  unsigned char* ws = (unsigned char*)d_ws;
  const size_t E2_BYTES = (size_t)V_ * H_ * 2;        // 65,536,000
  const size_t XB_BYTES = (size_t)3 * B_ * H_ * 4;    // 786,432
  unsigned short* E2  = (unsigned short*)ws;
  u32*            xbf = (u32*)(ws + E2_BYTES);
  unsigned short* hbf = (unsigned short*)(ws + E2_BYTES + XB_BYTES);

  k_init<<<768, 256, 0, stream>>>(xbf);
  k_e2<<<dim3(8, 250), 256, 0, stream>>>(emb, Wih, E2);
  k_scan<<<64, 512, 0, stream>>>(hist, Whh, E2, xbf, hbf,
                                 out + (size_t)B_ * V_);
  k_logits<<<500, 256, 0, stream>>>(hbf, Wcls, bcls, out);
}

// Round 15
// 1461.265 us; speedup vs baseline: 1.1696x; 1.1696x over previous
//
#include <hip/hip_runtime.h>
#include <hip/hip_bf16.h>
#include <cstdint>
#include <cstddef>

#define B_ 64
#define T_ 512
#define E_ 512
#define H_ 1024
#define V_ 32000

typedef __attribute__((ext_vector_type(8))) short bf16x8;
typedef __attribute__((ext_vector_type(4))) float f32x4;
typedef __attribute__((ext_vector_type(4))) float float4_t;
typedef unsigned long long ull;
typedef unsigned int u32;

static __device__ __forceinline__ unsigned short f2b(float f) {
  union { float f; u32 u; } v; v.f = f;
  u32 u = v.u;
  u32 r = (u + 0x7FFFu + ((u >> 16) & 1u)) >> 16;  // RNE
  return (unsigned short)r;
}
static __device__ __forceinline__ float b2f(unsigned short s) {
  union { u32 u; float f; } v; v.u = ((u32)s) << 16;
  return v.f;
}
// fast tanh: 1 - 2/(e^{2x}+1); v_exp_f32 + v_rcp_f32. rel err ~1e-6 << bf16.
static __device__ __forceinline__ float ftanh(float x) {
  float z = __builtin_amdgcn_exp2f(x * 2.8853900817779268f);  // e^{2x}
  return 1.0f - 2.0f * __builtin_amdgcn_rcpf(z + 1.0f);
}
static __device__ __forceinline__ bf16x8 cvt8(const float* p) {
  bf16x8 r;
#pragma unroll
  for (int i = 0; i < 8; i++) r[i] = (short)f2b(p[i]);
  return r;
}
// relaxed agent-scope (sc1) ops: coherent at MALL, no cache maintenance
static __device__ __forceinline__ ull ald(const ull* p) {
  return __hip_atomic_load(p, __ATOMIC_RELAXED, __HIP_MEMORY_SCOPE_AGENT);
}
static __device__ __forceinline__ void ast64(ull* p, ull v) {
  __hip_atomic_store(p, v, __ATOMIC_RELAXED, __HIP_MEMORY_SCOPE_AGENT);
}
static __device__ __forceinline__ void ast32(u32* p, u32 v) {
  __hip_atomic_store(p, v, __ATOMIC_RELAXED, __HIP_MEMORY_SCOPE_AGENT);
}
// LDS swizzle for 128-byte rows: spread rows across banks
static __device__ __forceinline__ int swz128(int row, int byte_off) {
  return row * 128 + (byte_off ^ ((row & 7) << 4));
}

// ---------------- init: clear epoch-tagged exchange buffers ----------------
// MUST run every launch: tags surviving a graph replay would short-circuit
// the waits (forbidden cross-call state). 3*64*1024 = 196608 u32.
__global__ void k_init(u32* xb) {
  int i = blockIdx.x * blockDim.x + threadIdx.x;
  ast32(xb + i, 0u);
}

// ---------------- E2 = emb @ W_ih^T  [V,H] bf16 ----------------
// 128x128 tile, 4 waves, 2x8 frags/wave, BK=64. grid (8, 250).
__global__ __launch_bounds__(256)
void k_e2(const float* __restrict__ emb, const float* __restrict__ Wih,
          unsigned short* __restrict__ E2) {
  __shared__ unsigned char As[128 * 128];
  __shared__ unsigned char Bs[128 * 128];
  const int tid = threadIdx.x;
  const int lane = tid & 63;
  const int w = tid >> 6;                   // 0..3 (M sub-tile of 32 rows)
  const int n0 = blockIdx.x * 128;          // over H
  const int m0 = blockIdx.y * 128;          // over V
  f32x4 acc[2][8];
#pragma unroll
  for (int mi = 0; mi < 2; mi++)
#pragma unroll
    for (int nt = 0; nt < 8; nt++) acc[mi][nt] = (f32x4)0.0f;

  for (int kc = 0; kc < E_ / 64; kc++) {
    const int k0 = kc * 64;
    __syncthreads();
#pragma unroll
    for (int it = 0; it < 8; it++) {
      int idx = tid + it * 256;             // 0..2047 chunks of f32x4
      int r = idx >> 4;                     // 0..127
      int k4 = (idx & 15) * 4;              // 0..60
      float ta[4], tb[4];
      *(float4_t*)ta = *(const float4_t*)(emb + (size_t)(m0 + r) * E_ + k0 + k4);
      *(float4_t*)tb = *(const float4_t*)(Wih + (size_t)(n0 + r) * E_ + k0 + k4);
      unsigned short pa[4], pb[4];
#pragma unroll
      for (int q = 0; q < 4; q++) { pa[q] = f2b(ta[q]); pb[q] = f2b(tb[q]); }
      *(ull*)(As + swz128(r, k4 * 2)) = *(ull*)pa;
      *(ull*)(Bs + swz128(r, k4 * 2)) = *(ull*)pb;
    }
    __syncthreads();
#pragma unroll
    for (int kk = 0; kk < 2; kk++) {
      int kb = kk * 64 + (lane >> 4) * 16;
      bf16x8 a0 = *(const bf16x8*)(As + swz128(w * 32 + (lane & 15), kb));
      bf16x8 a1 = *(const bf16x8*)(As + swz128(w * 32 + 16 + (lane & 15), kb));
#pragma unroll
      for (int nt = 0; nt < 8; nt++) {
        bf16x8 b = *(const bf16x8*)(Bs + swz128(nt * 16 + (lane & 15), kb));
        acc[0][nt] = __builtin_amdgcn_mfma_f32_16x16x32_bf16(a0, b, acc[0][nt], 0, 0, 0);
        acc[1][nt] = __builtin_amdgcn_mfma_f32_16x16x32_bf16(a1, b, acc[1][nt], 0, 0, 0);
      }
    }
  }
#pragma unroll
  for (int mi = 0; mi < 2; mi++)
#pragma unroll
    for (int nt = 0; nt < 8; nt++)
#pragma unroll
      for (int reg = 0; reg < 4; reg++) {
        int row = m0 + w * 32 + mi * 16 + (lane >> 4) * 4 + reg;
        int col = n0 + nt * 16 + (lane & 15);
        E2[(size_t)row * H_ + col] = f2b(acc[mi][nt][reg]);
      }
}

// ---------------- persistent scan over T ----------------
// R13 champion, exact: R10 geometry (8 groups x 8 blocks x 8 waves) +
// R11 tagged protocol (h word = (t+1)<<16 | bf16 via sc1; pull IS the poll;
// triple buffer, 2-hop WAR proof) + ftanh. Pull loads issued AFTER the xi
// gather, immediately before the tag check (R14 showed hoisting them earlier
// samples staler data -> more retries -> +19%). Spin-loop live set = 8 ull
// (R12 lesson: unified reg file exactly full; never widen the spin loop).
__global__ __launch_bounds__(512, 1)
void k_scan(const int* __restrict__ hist, const float* __restrict__ Whh,
            const unsigned short* __restrict__ E2,
            u32* __restrict__ xb,         // [3][64][1024] tagged words
            unsigned short* __restrict__ hbf, float* __restrict__ out_h) {
  const int tid = threadIdx.x;
  const int lane = tid & 63;
  const int w = tid >> 6;                 // wave id 0..7
  const int bid = blockIdx.x;
  const int g = bid & 7;                  // group (batch rows 8g..8g+8)
  const int j = bid >> 3;                 // col-slice id 0..7
  const int row0 = g * 8;                 // global batch-row base
  const int wcol0 = j * 128 + w * 16;     // this wave's 16 output cols

  __shared__ unsigned char hs[8 * 2048];  // h slice [8 rows][1024] bf16, swz

  const int ar = lane & 15;               // frag row: outcol (A) / batch (B,D)
  const int a7 = ar & 7;                  // valid batch row index
  const int hi = lane >> 4;               // 0..3 k-group

  // W-frags (MFMA A): lane holds W_hh[wcol0+ar][kk*32 + hi*8 .. +8)
  bf16x8 Wreg[32];
  {
    const float* wrow = Whh + (size_t)(wcol0 + ar) * H_ + hi * 8;
#pragma unroll
    for (int kk = 0; kk < 32; kk++) {
      float tmp[8];
      *(float4_t*)(tmp)     = *(const float4_t*)(wrow + kk * 32);
      *(float4_t*)(tmp + 4) = *(const float4_t*)(wrow + kk * 32 + 4);
      Wreg[kk] = cvt8(tmp);
    }
  }

  for (int t = 0; t < T_; t++) {
    // xi gather: ONE 8B load per lane — E2[tok][wcol0 + hi*4 .. +4)
    float xiv[4];
    {
      const int tok = hist[(size_t)(row0 + a7) * T_ + t];
      const ull xw = *(const ull*)(E2 + (size_t)tok * H_ + wcol0 + hi * 4);
      xiv[0] = b2f((unsigned short)xw);
      xiv[1] = b2f((unsigned short)(xw >> 16));
      xiv[2] = b2f((unsigned short)(xw >> 32));
      xiv[3] = b2f((unsigned short)(xw >> 48));
    }

    f32x4 acc0 = (f32x4)0.0f, acc1 = (f32x4)0.0f;

    if (t > 0) {
      // ---- self-validating pull: wave w pulls row row0+w of buf[(t-1)%3]
      // (1024 tagged u32 = 512 ull; lane reads ull lane+64i, i=0..7) ----
      const u32* rbuf = xb + (size_t)((t + 2) % 3) * (B_ * H_);
      const ull* src = (const ull*)(rbuf + (size_t)(row0 + w) * H_);
      const u32 tagv = (u32)t << 16;
      ull hv[8];
      for (;;) {
#pragma unroll
        for (int i = 0; i < 8; i++) hv[i] = ald(src + lane + 64 * i);
        u32 bad = 0;
#pragma unroll
        for (int i = 0; i < 8; i++)
          bad |= (((u32)hv[i] ^ tagv) | ((u32)(hv[i] >> 32) ^ tagv)) &
                 0xFFFF0000u;
        if (__all(bad == 0)) break;
        __builtin_amdgcn_s_sleep(1);
      }
      // strip tags, stage to LDS (same layout/swizzle as R10/R11)
      {
        unsigned char* hsb = hs + w * 2048;
        const int sw = w << 4;
#pragma unroll
        for (int i = 0; i < 8; i++) {
          u32 p = ((u32)hv[i] & 0xFFFFu) | ((u32)(hv[i] >> 32) << 16);
          *(u32*)(hsb + ((lane * 4 + i * 256) ^ sw)) = p;
        }
      }
      __syncthreads();

      // D[m=outcol][n=batch] = sum_k W[outcol][k] * h[batch][k]
      const unsigned char* brow = hs + a7 * 2048;
      const int swb = a7 << 4;
#pragma unroll
      for (int kk = 0; kk < 32; kk += 2) {
        bf16x8 b0 = *(const bf16x8*)(brow + (((kk)     * 64 + hi * 16) ^ swb));
        bf16x8 b1 = *(const bf16x8*)(brow + (((kk + 1) * 64 + hi * 16) ^ swb));
        acc0 = __builtin_amdgcn_mfma_f32_16x16x32_bf16(Wreg[kk],     b0, acc0, 0, 0, 0);
        acc1 = __builtin_amdgcn_mfma_f32_16x16x32_bf16(Wreg[kk + 1], b1, acc1, 0, 0, 0);
      }
    }

    // epilogue: tagged store — fire-and-forget (store IS the signal)
    if (ar < 8) {
      float hval[4];
#pragma unroll
      for (int reg = 0; reg < 4; reg++)
        hval[reg] = ftanh(acc0[reg] + acc1[reg] + xiv[reg]);
      const u32 tagw = (u32)(t + 1) << 16;
      ull lo = (ull)(tagw | f2b(hval[0])) | ((ull)(tagw | f2b(hval[1])) << 32);
      ull hi2 = (ull)(tagw | f2b(hval[2])) | ((ull)(tagw | f2b(hval[3])) << 32);
      u32* wbuf = xb + (size_t)(t % 3) * (B_ * H_);
      ull* dst = (ull*)(wbuf + (size_t)(row0 + ar) * H_ + wcol0 + hi * 4);
      ast64(dst, lo);
      ast64(dst + 1, hi2);
      if (t == T_ - 1) {
        float4_t o = {hval[0], hval[1], hval[2], hval[3]};
        *(float4_t*)(out_h + (size_t)(row0 + ar) * H_ + wcol0 + hi * 4) = o;
        unsigned short* hp = hbf + (size_t)(row0 + ar) * H_ + wcol0 + hi * 4;
        hp[0] = f2b(hval[0]); hp[1] = f2b(hval[1]);
        hp[2] = f2b(hval[2]); hp[3] = f2b(hval[3]);
      }
    }
  }
}

// ---------------- logits = h_final @ W_cls^T + b ----------------
// grid 500 blocks (64 vocab cols each), 256 threads
__global__ __launch_bounds__(256)
void k_logits(const unsigned short* __restrict__ hb,
              const float* __restrict__ Wcls, const float* __restrict__ bcls,
              float* __restrict__ out) {
  __shared__ unsigned char Bs[64 * 128];
  const int tid = threadIdx.x;
  const int lane = tid & 63;
  const int w = tid >> 6;
  const int n0 = blockIdx.x * 64;
  f32x4 acc[4];
#pragma unroll
  for (int i = 0; i < 4; i++) acc[i] = (f32x4)0.0f;

  for (int kc = 0; kc < H_ / 64; kc++) {
    const int k0 = kc * 64;
    __syncthreads();
#pragma unroll
    for (int it = 0; it < 2; it++) {
      int idx = tid + it * 256;
      int r = idx >> 3;
      int k = (idx & 7) * 8;
      float tmp[8];
      *(float4_t*)(tmp)     = *(const float4_t*)(Wcls + (size_t)(n0 + r) * H_ + k0 + k);
      *(float4_t*)(tmp + 4) = *(const float4_t*)(Wcls + (size_t)(n0 + r) * H_ + k0 + k + 4);
      *(bf16x8*)(Bs + swz128(r, k * 2)) = cvt8(tmp);
    }
    __syncthreads();
#pragma unroll
    for (int kk = 0; kk < 2; kk++) {
      const unsigned short* ap =
          hb + (size_t)(w * 16 + (lane & 15)) * H_ + k0 + kk * 32 + (lane >> 4) * 8;
      bf16x8 a = *(const bf16x8*)ap;
      int kb = kk * 64 + (lane >> 4) * 16;
#pragma unroll
      for (int nt = 0; nt < 4; nt++) {
        bf16x8 b = *(const bf16x8*)(Bs + swz128(nt * 16 + (lane & 15), kb));
        acc[nt] = __builtin_amdgcn_mfma_f32_16x16x32_bf16(a, b, acc[nt], 0, 0, 0);
      }
    }
  }
#pragma unroll
  for (int nt = 0; nt < 4; nt++) {
    int col = n0 + nt * 16 + (lane & 15);
    float bias = bcls[col];
#pragma unroll
    for (int reg = 0; reg < 4; reg++) {
      int row = w * 16 + (lane >> 4) * 4 + reg;
      out[(size_t)row * V_ + col] = acc[nt][reg] + bias;
    }
  }
}

extern "C" void kernel_launch(void* const* d_in, const int* in_sizes, int n_in,
                              void* d_out, int out_size, void* d_ws, size_t ws_size,
                              hipStream_t stream) {
  const int*   hist = (const int*)d_in[0];
  const float* emb  = (const float*)d_in[1];
  const float* Wih  = (const float*)d_in[2];
  const float* Whh  = (const float*)d_in[3];
  const float* Wcls = (const float*)d_in[4];
  const float* bcls = (const float*)d_in[5];
  float* out = (float*)d_out;

  unsigned char* ws = (unsigned char*)d_ws;
  const size_t E2_BYTES = (size_t)V_ * H_ * 2;        // 65,536,000
  const size_t XB_BYTES = (size_t)3 * B_ * H_ * 4;    // 786,432
  unsigned short* E2  = (unsigned short*)ws;
  u32*            xbf = (u32*)(ws + E2_BYTES);
  unsigned short* hbf = (unsigned short*)(ws + E2_BYTES + XB_BYTES);

  k_init<<<768, 256, 0, stream>>>(xbf);
  k_e2<<<dim3(8, 250), 256, 0, stream>>>(emb, Wih, E2);
  k_scan<<<64, 512, 0, stream>>>(hist, Whh, E2, xbf, hbf,
                                 out + (size_t)B_ * V_);
  k_logits<<<500, 256, 0, stream>>>(hbf, Wcls, bcls, out);
}